// Round 6
// baseline (162.451 us; speedup 1.0000x reference)
//
#include <hip/hip_runtime.h>
#include <hip/hip_bf16.h>

#define NN   100000   // nodes
#define EE   500000   // edges
#define MPAD 100096   // 782 * 128

using bf16x8 = __attribute__((ext_vector_type(8))) short;
using f32x4  = __attribute__((ext_vector_type(4))) float;
using u16x8  = __attribute__((ext_vector_type(8))) unsigned short;

__device__ __forceinline__ unsigned short f2bf(float f) {
  unsigned int x = __builtin_bit_cast(unsigned int, f);
  x += 0x7fffu + ((x >> 16) & 1u);           // round-to-nearest-even
  return (unsigned short)(x >> 16);
}
__device__ __forceinline__ float bf2f(unsigned short u) {
  unsigned int x = ((unsigned int)u) << 16;
  return __builtin_bit_cast(float, x);
}
// HW RNE cvt (compiler emits v_cvt_pk_bf16_f32 for pairs)
__device__ __forceinline__ unsigned short f2bh(float f) {
  return __builtin_bit_cast(unsigned short, __float2bfloat16(f));
}

// ---------------- Pass 1: WT[j][k] = bf16(W1[k + 256*(j>=256)][j&255]) ----------------
__global__ void wprep_kernel(const float* __restrict__ W1, unsigned short* __restrict__ WT) {
  int id = blockIdx.x * blockDim.x + threadIdx.x;
  if (id >= 512 * 32) return;
  int j  = id >> 5;        // 0..511
  int cg = id & 31;        // 8-element k-chunk
  int jc = j & 255;
  int kb = (cg << 3) + ((j >= 256) ? 256 : 0);
  u16x8 v;
#pragma unroll
  for (int t = 0; t < 8; ++t)
    v[t] = f2bf(W1[(size_t)(kb + t) * 256 + jc]);
  *reinterpret_cast<u16x8*>(WT + (size_t)j * 256 + (cg << 3)) = v;
}

// ---------------- Pass 2: R[MPAD][512] bf16 = emb @ WT^T (+ b1 on src half) ----------------
// 256 thr = 4 waves (2x2), tile 128(M) x 128(N), K=256 = 8 slices of 32.
// A-tile staged to LDS ONCE as bf16 (64 KB, chunk-XOR swizzle, R1-proven 0-conflict);
// exactly ONE __syncthreads per block. B-fragments stream straight from WT (L2-resident,
// 16B/lane, 4-deep register rotation issued 4 K-steps ahead). K-loop is barrier-free
// straight-line code -> compiler emits counted lgkm/vmcnt pipelining.
__global__ __launch_bounds__(256, 2) void gemm_pq(const float* __restrict__ emb,
                                                  const unsigned short* __restrict__ WT,
                                                  const float* __restrict__ b1,
                                                  unsigned short* __restrict__ R) {
  __shared__ unsigned short ldsA[8][128 * 32];   // [k-slice][row*32 + swizzled chunk*8]

  const int t    = threadIdx.x;
  const int lane = t & 63;
  const int wave = t >> 6;
  const int wrow = wave >> 1, wcol = wave & 1;
  // XCD-bijective swizzle (3128 = 8*391); 4 n-siblings of an m-tile share an XCD L2.
  const int bid = (int)blockIdx.x;
  const int lid = (bid & 7) * 391 + (bid >> 3);
  const int m0 = (lid >> 2) * 128;
  const int n0 = (lid & 3) * 128;

  // ---- A staging (once): thread -> row a_r = t>>1, half a_h = t&1 (16 fp32 per slice)
  const int a_r = t >> 1, a_h = t & 1;
  int arow_g = m0 + a_r; if (arow_g >= NN) arow_g = NN - 1;   // clamp; pad rows unused
  const float* aSrc = emb + (size_t)arow_g * 256 + (a_h << 4);
  const int swzA = (a_r >> 1) & 3;
  const int aW0  = a_r * 32 + ((((a_h << 1) | 0) ^ swzA) << 3);
  const int aW1  = a_r * 32 + ((((a_h << 1) | 1) ^ swzA) << 3);
#pragma unroll
  for (int s = 0; s < 8; ++s) {
    float4 f0 = *(const float4*)(aSrc + s * 32);
    float4 f1 = *(const float4*)(aSrc + s * 32 + 4);
    float4 f2 = *(const float4*)(aSrc + s * 32 + 8);
    float4 f3 = *(const float4*)(aSrc + s * 32 + 12);
    u16x8 w0, w1;
    w0[0] = f2bh(f0.x); w0[1] = f2bh(f0.y); w0[2] = f2bh(f0.z); w0[3] = f2bh(f0.w);
    w0[4] = f2bh(f1.x); w0[5] = f2bh(f1.y); w0[6] = f2bh(f1.z); w0[7] = f2bh(f1.w);
    w1[0] = f2bh(f2.x); w1[1] = f2bh(f2.y); w1[2] = f2bh(f2.z); w1[3] = f2bh(f2.w);
    w1[4] = f2bh(f3.x); w1[5] = f2bh(f3.y); w1[6] = f2bh(f3.z); w1[7] = f2bh(f3.w);
    *(u16x8*)&ldsA[s][aW0] = w0;
    *(u16x8*)&ldsA[s][aW1] = w1;
  }

  // ---- fragment addressing
  const int fr = lane & 15, fq = lane >> 4;
  int aoff[4];
#pragma unroll
  for (int m = 0; m < 4; ++m) {
    const int r = wrow * 64 + 16 * m + fr;
    aoff[m] = r * 32 + ((fq ^ ((r >> 1) & 3)) << 3);
  }
  const unsigned short* bRow[4];
#pragma unroll
  for (int n = 0; n < 4; ++n)
    bRow[n] = WT + (size_t)(n0 + wcol * 64 + 16 * n + fr) * 256 + (fq << 3);

  // ---- B preload: 4 K-slices deep (global, independent of LDS -> overlaps staging drain)
  bf16x8 bv[4][4];
#pragma unroll
  for (int s = 0; s < 4; ++s)
#pragma unroll
    for (int n = 0; n < 4; ++n)
      bv[s][n] = *(const bf16x8*)(bRow[n] + (s << 5));

  __syncthreads();                                 // the only barrier

  f32x4 acc[4][4] = {};
  bf16x8 av[2][4];
#pragma unroll
  for (int m = 0; m < 4; ++m) av[0][m] = *(const bf16x8*)&ldsA[0][aoff[m]];

#pragma unroll
  for (int ks = 0; ks < 8; ++ks) {
    const int cur = ks & 1;
    if (ks < 7) {                                  // prefetch next A frags (LDS, no barrier)
#pragma unroll
      for (int m = 0; m < 4; ++m)
        av[cur ^ 1][m] = *(const bf16x8*)&ldsA[ks + 1][aoff[m]];
    }
#pragma unroll
    for (int m = 0; m < 4; ++m)
#pragma unroll
      for (int n = 0; n < 4; ++n)
        acc[m][n] = __builtin_amdgcn_mfma_f32_16x16x32_bf16(av[cur][m], bv[ks & 3][n],
                                                            acc[m][n], 0, 0, 0);
    if (ks < 4) {                                  // refill rotation slot 4 steps ahead
#pragma unroll
      for (int n = 0; n < 4; ++n)
        bv[ks & 3][n] = *(const bf16x8*)(bRow[n] + ((ks + 4) << 5));
    }
  }

  // epilogue: col = lane&15 (+16n), row = (lane>>4)*4 + i; m-outer/n-inner (full 128B lines)
  float bn[4];
#pragma unroll
  for (int n = 0; n < 4; ++n) {
    const int c = n0 + wcol * 64 + 16 * n + fr;
    bn[n] = (c < 256) ? b1[c] : 0.f;
  }
#pragma unroll
  for (int m = 0; m < 4; ++m) {
    const int r0 = m0 + wrow * 64 + 16 * m + (fq << 2);
#pragma unroll
    for (int n = 0; n < 4; ++n) {
      const int c = n0 + wcol * 64 + 16 * n + fr;
#pragma unroll
      for (int i = 0; i < 4; ++i)
        R[(size_t)(r0 + i) * 512 + c] = f2bh(acc[m][n][i] + bn[n]);
    }
  }
}

// ---------------- Pass 3: 8 edges per wave-iteration, 2 edges in flight via lane split ----
// score[e] = b2 + sum_j relu(R[src][j] + R[dst][256+j]) * W2[j]   (b1 pre-folded into R)
__global__ __launch_bounds__(256) void edge_kernel(const int* __restrict__ idx,
                                                   const unsigned short* __restrict__ R,
                                                   const float* __restrict__ W2,
                                                   const float* __restrict__ b2,
                                                   float* __restrict__ out) {
  const int lane  = threadIdx.x & 63;
  const int half  = lane >> 5;         // which of the 2 concurrent edges this lane serves
  const int l     = lane & 31;         // 32 lanes x 8 channels = 256 channels
  const int gwave = (int)((blockIdx.x * blockDim.x + threadIdx.x) >> 6);
  const int nwave = (int)((gridDim.x * blockDim.x) >> 6);
  const float4 w0 = *(const float4*)(W2 + (l << 3));
  const float4 w1 = *(const float4*)(W2 + (l << 3) + 4);
  const float bias = b2[0];

  for (int c = gwave; c < (EE / 8); c += nwave) {
    const int e0 = c << 3;
    int s[4], d[4];
#pragma unroll
    for (int u = 0; u < 4; ++u) {                // edge for this lane: e0 + 2u + half
      s[u] = idx[e0 + (u << 1) + half];
      d[u] = idx[EE + e0 + (u << 1) + half];
    }
    u16x8 ga[4], gb[4];
#pragma unroll
    for (int u = 0; u < 4; ++u) {                // issue all 16 gathers before reducing
      ga[u] = *(const u16x8*)(R + (size_t)s[u] * 512 + (l << 3));
      gb[u] = *(const u16x8*)(R + (size_t)d[u] * 512 + 256 + (l << 3));
    }
#pragma unroll
    for (int u = 0; u < 4; ++u) {
      float acc;
      acc  = fmaxf(bf2f((unsigned short)ga[u][0]) + bf2f((unsigned short)gb[u][0]), 0.f) * w0.x;
      acc += fmaxf(bf2f((unsigned short)ga[u][1]) + bf2f((unsigned short)gb[u][1]), 0.f) * w0.y;
      acc += fmaxf(bf2f((unsigned short)ga[u][2]) + bf2f((unsigned short)gb[u][2]), 0.f) * w0.z;
      acc += fmaxf(bf2f((unsigned short)ga[u][3]) + bf2f((unsigned short)gb[u][3]), 0.f) * w0.w;
      acc += fmaxf(bf2f((unsigned short)ga[u][4]) + bf2f((unsigned short)gb[u][4]), 0.f) * w1.x;
      acc += fmaxf(bf2f((unsigned short)ga[u][5]) + bf2f((unsigned short)gb[u][5]), 0.f) * w1.y;
      acc += fmaxf(bf2f((unsigned short)ga[u][6]) + bf2f((unsigned short)gb[u][6]), 0.f) * w1.z;
      acc += fmaxf(bf2f((unsigned short)ga[u][7]) + bf2f((unsigned short)gb[u][7]), 0.f) * w1.w;
#pragma unroll
      for (int off = 16; off > 0; off >>= 1) acc += __shfl_xor(acc, off, 64);
      if (l == 0) out[e0 + (u << 1) + half] = acc + bias;
    }
  }
}

// ---------------- Fallback (only if ws is too small): direct, slow, correct ----------------
__global__ __launch_bounds__(256) void fallback_kernel(const float* __restrict__ emb,
                                                       const int* __restrict__ idx,
                                                       const float* __restrict__ W1,
                                                       const float* __restrict__ b1,
                                                       const float* __restrict__ W2,
                                                       const float* __restrict__ b2,
                                                       float* __restrict__ out) {
  __shared__ float feats[512];
  __shared__ float red[256];
  const int t = threadIdx.x;
  for (int e = blockIdx.x; e < EE; e += gridDim.x) {
    __syncthreads();
    const int s = idx[e], d = idx[EE + e];
    feats[t]       = emb[(size_t)s * 256 + t];
    feats[256 + t] = emb[(size_t)d * 256 + t];
    __syncthreads();
    float h = b1[t];
    for (int k = 0; k < 512; ++k) h += feats[k] * W1[k * 256 + t];
    red[t] = fmaxf(h, 0.f) * W2[t];
    __syncthreads();
    for (int off = 128; off > 0; off >>= 1) {
      if (t < off) red[t] += red[t + off];
      __syncthreads();
    }
    if (t == 0) out[e] = red[0] + b2[0];
  }
}

extern "C" void kernel_launch(void* const* d_in, const int* in_sizes, int n_in,
                              void* d_out, int out_size, void* d_ws, size_t ws_size,
                              hipStream_t stream) {
  const float* emb = (const float*)d_in[0];
  const int*   idx = (const int*)d_in[1];
  const float* W1  = (const float*)d_in[2];
  const float* b1  = (const float*)d_in[3];
  const float* W2  = (const float*)d_in[4];
  const float* b2  = (const float*)d_in[5];
  float* out = (float*)d_out;

  const size_t wt_elems = (size_t)512 * 256;
  const size_t r_elems  = (size_t)MPAD * 512;
  const size_t need = (wt_elems + r_elems) * sizeof(unsigned short);

  if (ws_size < need) {
    fallback_kernel<<<4096, 256, 0, stream>>>(emb, idx, W1, b1, W2, b2, out);
    return;
  }

  unsigned short* WT = (unsigned short*)d_ws;
  unsigned short* R  = WT + wt_elems;

  wprep_kernel<<<64, 256, 0, stream>>>(W1, WT);
  gemm_pq<<<(MPAD / 128) * 4, 256, 0, stream>>>(emb, WT, b1, R);
  edge_kernel<<<2048, 256, 0, stream>>>(idx, R, W2, b2, out);
}

// Round 7
// 150.347 us; speedup vs baseline: 1.0805x; 1.0805x over previous
//
#include <hip/hip_runtime.h>

#define NN   100000   // nodes
#define EE   500000   // edges
#define MPAD 100096   // 782 * 128

using bf16x8 = __attribute__((ext_vector_type(8))) short;
using f32x4  = __attribute__((ext_vector_type(4))) float;
using u16x8  = __attribute__((ext_vector_type(8))) unsigned short;

__device__ __forceinline__ unsigned short f2bf(float f) {
  unsigned int x = __builtin_bit_cast(unsigned int, f);
  x += 0x7fffu + ((x >> 16) & 1u);           // round-to-nearest-even
  return (unsigned short)(x >> 16);
}
__device__ __forceinline__ float bf2f(unsigned short u) {
  unsigned int x = ((unsigned int)u) << 16;
  return __builtin_bit_cast(float, x);
}

// ---------------- Pass 1: WT[j][k] = bf16(W1[k + 256*(j>=256)][j&255]) ----------------
__global__ void wprep_kernel(const float* __restrict__ W1, unsigned short* __restrict__ WT) {
  int id = blockIdx.x * blockDim.x + threadIdx.x;
  if (id >= 512 * 32) return;
  int j  = id >> 5;        // 0..511
  int cg = id & 31;        // 8-element k-chunk
  int jc = j & 255;
  int kb = (cg << 3) + ((j >= 256) ? 256 : 0);
  u16x8 v;
#pragma unroll
  for (int t = 0; t < 8; ++t)
    v[t] = f2bf(W1[(size_t)(kb + t) * 256 + jc]);
  *reinterpret_cast<u16x8*>(WT + (size_t)j * 256 + (cg << 3)) = v;
}

// ---------------- Pass 2: R[MPAD][512] bf16 = emb[MPAD][256] @ WT^T ----------------
// BYTE-EXACT copy of the R1 gemm (the ~50us-by-accounting variant): 512 thr = 8 waves
// (2x4), tile 128x256, BK=32, double-buffered LDS, reg-staged A and B, one barrier per
// K-step, no b1 fold, manual f2bf, no launch_bounds, no XCD swizzle.
__global__ __launch_bounds__(512) void gemm_pq(const float* __restrict__ emb,
                                               const unsigned short* __restrict__ WT,
                                               unsigned short* __restrict__ R) {
  __shared__ unsigned short ldsA[2][128 * 32];
  __shared__ unsigned short ldsB[2][256 * 32];

  const int t    = threadIdx.x;
  const int lane = t & 63;
  const int wave = t >> 6;
  const int wrow = wave >> 2;                    // 0..1
  const int wcol = wave & 3;                     // 0..3
  const int m0   = (int)(blockIdx.x >> 1) * 128;
  const int n0   = (int)(blockIdx.x & 1) * 256;

  // A staging: thread -> (row = t>>2, chunk ac = t&3) of the 128x32 tile
  const int arow = t >> 2, ac = t & 3;
  const bool aOk = (m0 + arow) < NN;
  const float* aSrc = emb + (size_t)(m0 + arow) * 256 + (ac << 3);
  const int aW = arow * 32 + ((ac ^ ((arow >> 1) & 3)) << 3);

  // B staging: thread -> (row = t>>1, half bh = t&1 -> chunks 2bh, 2bh+1) of 256x32 tile
  const int brow = t >> 1, bh = t & 1;
  const unsigned short* bSrc = WT + (size_t)(n0 + brow) * 256 + (bh << 4);
  const int f_b = (brow >> 1) & 3;
  const int bW0 = brow * 32 + ((((bh << 1) | 0) ^ f_b) << 3);
  const int bW1 = brow * 32 + ((((bh << 1) | 1) ^ f_b) << 3);

  // fragment read offsets (lane -> row = 16m + (lane&15), k-chunk = lane>>4)
  const int fr = lane & 15, fq = lane >> 4;
  int aoff[4], boff[4];
#pragma unroll
  for (int m = 0; m < 4; ++m) {
    int r = wrow * 64 + 16 * m + fr;
    aoff[m] = r * 32 + ((fq ^ ((r >> 1) & 3)) << 3);
  }
#pragma unroll
  for (int n = 0; n < 4; ++n) {
    int r = wcol * 64 + 16 * n + fr;
    boff[n] = r * 32 + ((fq ^ ((r >> 1) & 3)) << 3);
  }

  f32x4 acc[4][4] = {};

  // prologue: stage ks=0 into buffer 0
  {
    float4 a0, a1;
    if (aOk) { a0 = *(const float4*)aSrc; a1 = *(const float4*)(aSrc + 4); }
    else     { a0 = make_float4(0.f, 0.f, 0.f, 0.f); a1 = a0; }
    u16x8 b0 = *(const u16x8*)bSrc;
    u16x8 b1 = *(const u16x8*)(bSrc + 8);
    u16x8 aw;
    aw[0] = f2bf(a0.x); aw[1] = f2bf(a0.y); aw[2] = f2bf(a0.z); aw[3] = f2bf(a0.w);
    aw[4] = f2bf(a1.x); aw[5] = f2bf(a1.y); aw[6] = f2bf(a1.z); aw[7] = f2bf(a1.w);
    *(u16x8*)&ldsA[0][aW]  = aw;
    *(u16x8*)&ldsB[0][bW0] = b0;
    *(u16x8*)&ldsB[0][bW1] = b1;
  }
  __syncthreads();

#pragma unroll
  for (int ks = 0; ks < 8; ++ks) {
    const int p = ks & 1;
    float4 na0, na1; u16x8 nb0, nb1;
    if (ks < 7) {                                   // issue next-tile global loads early
      const float* as = aSrc + ((ks + 1) << 5);
      if (aOk) { na0 = *(const float4*)as; na1 = *(const float4*)(as + 4); }
      else     { na0 = make_float4(0.f, 0.f, 0.f, 0.f); na1 = na0; }
      const unsigned short* bs = bSrc + ((ks + 1) << 5);
      nb0 = *(const u16x8*)bs;
      nb1 = *(const u16x8*)(bs + 8);
    }
    bf16x8 av[4], bv[4];
#pragma unroll
    for (int m = 0; m < 4; ++m) av[m] = *(const bf16x8*)&ldsA[p][aoff[m]];
#pragma unroll
    for (int n = 0; n < 4; ++n) bv[n] = *(const bf16x8*)&ldsB[p][boff[n]];
#pragma unroll
    for (int m = 0; m < 4; ++m)
#pragma unroll
      for (int n = 0; n < 4; ++n)
        acc[m][n] = __builtin_amdgcn_mfma_f32_16x16x32_bf16(av[m], bv[n], acc[m][n], 0, 0, 0);
    if (ks < 7) {                                   // write next tile into the other buffer
      u16x8 aw;
      aw[0] = f2bf(na0.x); aw[1] = f2bf(na0.y); aw[2] = f2bf(na0.z); aw[3] = f2bf(na0.w);
      aw[4] = f2bf(na1.x); aw[5] = f2bf(na1.y); aw[6] = f2bf(na1.z); aw[7] = f2bf(na1.w);
      *(u16x8*)&ldsA[p ^ 1][aW]  = aw;
      *(u16x8*)&ldsB[p ^ 1][bW0] = nb0;
      *(u16x8*)&ldsB[p ^ 1][bW1] = nb1;
    }
    __syncthreads();
  }

  // epilogue: C/D layout col = lane&15, row = (lane>>4)*4 + reg
#pragma unroll
  for (int m = 0; m < 4; ++m) {
    const int r0 = m0 + wrow * 64 + 16 * m + (fq << 2);
#pragma unroll
    for (int n = 0; n < 4; ++n) {
      const int c = n0 + wcol * 64 + 16 * n + fr;
#pragma unroll
      for (int i = 0; i < 4; ++i)
        R[(size_t)(r0 + i) * 512 + c] = f2bf(acc[m][n][i]);
    }
  }
}

// ---------------- Pass 3: 8 edges per wave-iteration, 2 edges in flight via lane split ----
// score[e] = b2 + sum_j relu(R[src][j] + R[dst][256+j] + b1[j]) * W2[j]
__global__ __launch_bounds__(256) void edge_kernel(const int* __restrict__ idx,
                                                   const unsigned short* __restrict__ R,
                                                   const float* __restrict__ b1,
                                                   const float* __restrict__ W2,
                                                   const float* __restrict__ b2,
                                                   float* __restrict__ out) {
  const int lane  = threadIdx.x & 63;
  const int half  = lane >> 5;         // which of the 2 concurrent edges this lane serves
  const int l     = lane & 31;         // 32 lanes x 8 channels = 256 channels
  const int gwave = (int)((blockIdx.x * blockDim.x + threadIdx.x) >> 6);
  const int nwave = (int)((gridDim.x * blockDim.x) >> 6);
  const float4 w0  = *(const float4*)(W2 + (l << 3));
  const float4 w1  = *(const float4*)(W2 + (l << 3) + 4);
  const float4 c0  = *(const float4*)(b1 + (l << 3));
  const float4 c1  = *(const float4*)(b1 + (l << 3) + 4);
  const float bias = b2[0];

  for (int c = gwave; c < (EE / 8); c += nwave) {
    const int e0 = c << 3;
    int s[4], d[4];
#pragma unroll
    for (int u = 0; u < 4; ++u) {                // edge for this lane: e0 + 2u + half
      s[u] = idx[e0 + (u << 1) + half];
      d[u] = idx[EE + e0 + (u << 1) + half];
    }
    u16x8 ga[4], gb[4];
#pragma unroll
    for (int u = 0; u < 4; ++u) {                // issue all 16 gathers before reducing
      ga[u] = *(const u16x8*)(R + (size_t)s[u] * 512 + (l << 3));
      gb[u] = *(const u16x8*)(R + (size_t)d[u] * 512 + 256 + (l << 3));
    }
#pragma unroll
    for (int u = 0; u < 4; ++u) {
      float acc;
      acc  = fmaxf(bf2f((unsigned short)ga[u][0]) + bf2f((unsigned short)gb[u][0]) + c0.x, 0.f) * w0.x;
      acc += fmaxf(bf2f((unsigned short)ga[u][1]) + bf2f((unsigned short)gb[u][1]) + c0.y, 0.f) * w0.y;
      acc += fmaxf(bf2f((unsigned short)ga[u][2]) + bf2f((unsigned short)gb[u][2]) + c0.z, 0.f) * w0.z;
      acc += fmaxf(bf2f((unsigned short)ga[u][3]) + bf2f((unsigned short)gb[u][3]) + c0.w, 0.f) * w0.w;
      acc += fmaxf(bf2f((unsigned short)ga[u][4]) + bf2f((unsigned short)gb[u][4]) + c1.x, 0.f) * w1.x;
      acc += fmaxf(bf2f((unsigned short)ga[u][5]) + bf2f((unsigned short)gb[u][5]) + c1.y, 0.f) * w1.y;
      acc += fmaxf(bf2f((unsigned short)ga[u][6]) + bf2f((unsigned short)gb[u][6]) + c1.z, 0.f) * w1.z;
      acc += fmaxf(bf2f((unsigned short)ga[u][7]) + bf2f((unsigned short)gb[u][7]) + c1.w, 0.f) * w1.w;
#pragma unroll
      for (int off = 16; off > 0; off >>= 1) acc += __shfl_xor(acc, off, 64);
      if (l == 0) out[e0 + (u << 1) + half] = acc + bias;
    }
  }
}

// ---------------- Fallback (only if ws is too small): direct, slow, correct ----------------
__global__ __launch_bounds__(256) void fallback_kernel(const float* __restrict__ emb,
                                                       const int* __restrict__ idx,
                                                       const float* __restrict__ W1,
                                                       const float* __restrict__ b1,
                                                       const float* __restrict__ W2,
                                                       const float* __restrict__ b2,
                                                       float* __restrict__ out) {
  __shared__ float feats[512];
  __shared__ float red[256];
  const int t = threadIdx.x;
  for (int e = blockIdx.x; e < EE; e += gridDim.x) {
    __syncthreads();
    const int s = idx[e], d = idx[EE + e];
    feats[t]       = emb[(size_t)s * 256 + t];
    feats[256 + t] = emb[(size_t)d * 256 + t];
    __syncthreads();
    float h = b1[t];
    for (int k = 0; k < 512; ++k) h += feats[k] * W1[k * 256 + t];
    red[t] = fmaxf(h, 0.f) * W2[t];
    __syncthreads();
    for (int off = 128; off > 0; off >>= 1) {
      if (t < off) red[t] += red[t + off];
      __syncthreads();
    }
    if (t == 0) out[e] = red[0] + b2[0];
  }
}

extern "C" void kernel_launch(void* const* d_in, const int* in_sizes, int n_in,
                              void* d_out, int out_size, void* d_ws, size_t ws_size,
                              hipStream_t stream) {
  const float* emb = (const float*)d_in[0];
  const int*   idx = (const int*)d_in[1];
  const float* W1  = (const float*)d_in[2];
  const float* b1  = (const float*)d_in[3];
  const float* W2  = (const float*)d_in[4];
  const float* b2  = (const float*)d_in[5];
  float* out = (float*)d_out;

  const size_t wt_elems = (size_t)512 * 256;
  const size_t r_elems  = (size_t)MPAD * 512;
  const size_t need = (wt_elems + r_elems) * sizeof(unsigned short);

  if (ws_size < need) {
    fallback_kernel<<<4096, 256, 0, stream>>>(emb, idx, W1, b1, W2, b2, out);
    return;
  }

  unsigned short* WT = (unsigned short*)d_ws;
  unsigned short* R  = WT + wt_elems;

  wprep_kernel<<<64, 256, 0, stream>>>(W1, WT);
  gemm_pq<<<782 * 2, 512, 0, stream>>>(emb, WT, R);
  edge_kernel<<<2048, 256, 0, stream>>>(idx, R, b1, W2, b2, out);
}